// Round 5
// baseline (3761.951 us; speedup 1.0000x reference)
//
#include <hip/hip_runtime.h>

#define NPADC 40
#define NZ 26
#define NXI 120            // interior nx (seismo width)
#define NZP 106
#define NXP 200
#define NCELL (NZP * NXP)

#define KSTEPS 5
#define HALO (2 * KSTEPS)          // 10
#define TZ 7
#define TX 13
#define ZB 16                      // 15*7=105, last tzb=1
#define XB 16                      // 15*13=195, last txb=5
#define NBLOCKS (ZB * XB)          // 256
#define EXT_ZM (TZ + 2 * HALO)     // 27
#define EXT_XM (TX + 2 * HALO)     // 33  (constant LDS row stride)
#define LDSN (EXT_ZM * EXT_XM)     // 891
#define NTHREADS 256
#define SLOTS 4                    // ceil(LDSN / NTHREADS)

#define AGENT __HIP_MEMORY_SCOPE_AGENT

__device__ __forceinline__ float aload(float* p) {
    return __hip_atomic_load(p, __ATOMIC_RELAXED, AGENT);
}
__device__ __forceinline__ void astore(float* p, float v) {
    __hip_atomic_store(p, v, __ATOMIC_RELAXED, AGENT);
}

// ---- damp profile, matching _damp_profile in fp32 ----
__device__ __forceinline__ float dprof(int idx, int n) {
#pragma clang fp contract(off)
    float fi = (float)idx;
    float left = 1.0f, right = 1.0f;
    if (idx < NPADC) {
        float a = 0.015f * ((float)NPADC - fi);
        left = expf(-(a * a));
    }
    if (idx >= n - NPADC) {
        float a = 0.015f * (fi - (float)(n - NPADC - 1));
        right = expf(-(a * a));
    }
    return left * right;
}

// ---- one-time setup: coefficients into ws, init state buf0, zero flags ----
__global__ void setup_kernel(const float* __restrict__ vp,
                             const float* __restrict__ vs,
                             const float* __restrict__ den,
                             const float* __restrict__ ivec,
                             const float* __restrict__ temp,
                             float* __restrict__ coeff,
                             float* __restrict__ buf0,
                             unsigned* __restrict__ flags) {
#pragma clang fp contract(off)
    int i = blockIdx.x * blockDim.x + threadIdx.x;
    if (i < NBLOCKS) flags[i] = 0u;
    if (i >= NCELL) return;
    int z = i / NXP;
    int x = i - z * NXP;

    float dtx = ivec[3];

    int zi = z - NPADC; zi = zi < 0 ? 0 : (zi > NZ - 1 ? NZ - 1 : zi);
    int xi = x - NPADC; xi = xi < 0 ? 0 : (xi > NXI - 1 ? NXI - 1 : xi);
    float vpv = vp[zi * NXI + xi];
    float vsv = vs[zi * NXI + xi];
    float d = den[i];

    float cav = (vpv * vpv) * d;     // ca
    float cmv = (vsv * vsv) * d;     // cm
    coeff[0 * NCELL + i] = dtx / d;                        // b
    coeff[1 * NCELL + i] = dprof(z, NZP) * dprof(x, NXP);  // damp
    coeff[2 * NCELL + i] = cav;                            // ca
    coeff[3 * NCELL + i] = cav - 2.0f * cmv;               // cl
    coeff[4 * NCELL + i] = dtx * cmv;                      // dtx*cm

    for (int f = 0; f < 5; ++f)
        buf0[f * NCELL + i] = temp[f * NCELL + i];
}

// lds field order: 0=vx 1=vz 2=txx 3=tzz 4=txz ; coeffs live in registers
__global__ __launch_bounds__(NTHREADS)
void persist_kernel(const float* __restrict__ coeff,
                    float* __restrict__ buf0, float* __restrict__ buf1,
                    const float* __restrict__ ivec, const float* __restrict__ s,
                    const int* __restrict__ iszp, const int* __restrict__ isxp,
                    float* __restrict__ fields_out,
                    float* __restrict__ illum_out,
                    float* __restrict__ seismo,
                    unsigned* __restrict__ flags,
                    int nt) {
#pragma clang fp contract(off)
    __shared__ float lds[5][LDSN];
    __shared__ float lill[TZ * TX];

    const int tid = threadIdx.x;
    const int bid = blockIdx.x;
    const int zb = bid / XB, xb = bid - zb * XB;
    const int z0 = zb * TZ, x0 = xb * TX;
    const int tzb = (NZP - z0 < TZ) ? (NZP - z0) : TZ;   // 7 or 1
    const int txb = (NXP - x0 < TX) ? (NXP - x0) : TX;   // 13 or 5
    const int ez   = tzb + 2 * HALO;                      // <= 27
    const int extx = txb + 2 * HALO;                      // <= 33
    const float dt  = ivec[2];
    const float dtx = ivec[3];
    const int isz = *iszp, isx = *isxp;

    // ---- per-thread slot precompute (coords, wrap, ownership, coeffs) ----
    int rcA[SLOTS], gA[SLOTS], izA[SLOTS], ixA[SLOTS], seisA[SLOTS], lilA[SLOTS];
    float cb[SLOTS], cd[SLOTS], cca[SLOTS], ccl[SLOTS], cdtcm[SLOTS];
#pragma unroll
    for (int k = 0; k < SLOTS; ++k) {
        int rc = tid + k * NTHREADS;
        rcA[k] = rc;
        int iz = rc / EXT_XM, ix = rc - iz * EXT_XM;
        if (rc < LDSN && iz < ez && ix < extx) {
            izA[k] = iz; ixA[k] = ix;
            int gz = z0 - HALO + iz; gz += (gz < 0) ? NZP : 0; gz -= (gz >= NZP) ? NZP : 0;
            int gx = x0 - HALO + ix; gx += (gx < 0) ? NXP : 0; gx -= (gx >= NXP) ? NXP : 0;
            int g = gz * NXP + gx;
            gA[k] = g;
            cb[k]    = coeff[0 * NCELL + g];
            cd[k]    = coeff[1 * NCELL + g];
            cca[k]   = coeff[2 * NCELL + g];
            ccl[k]   = coeff[3 * NCELL + g];
            cdtcm[k] = coeff[4 * NCELL + g];
            int liz = iz - HALO, lix = ix - HALO;
            bool inter = (liz >= 0 && liz < tzb && lix >= 0 && lix < txb);
            int gzi = z0 + liz, gxi = x0 + lix;
            seisA[k] = (inter && gzi == NPADC + 1 && gxi >= NPADC && gxi < NPADC + NXI)
                           ? (gxi - NPADC) : -1;
            lilA[k] = inter ? (liz * TX + lix) : -1;
        } else {
            izA[k] = -1000; ixA[k] = -1000; gA[k] = 0; seisA[k] = -1; lilA[k] = -1;
            cb[k] = cd[k] = cca[k] = ccl[k] = cdtcm[k] = 0.0f;
        }
    }
    // source cell local index (injective: ez<=NZP, extx<=NXP)
    int lzs = isz - (z0 - HALO); lzs = ((lzs % NZP) + NZP) % NZP;
    int lxs = isx - (x0 - HALO); lxs = ((lxs % NXP) + NXP) % NXP;
    const int src_rc = (lzs < ez && lxs < extx) ? lzs * EXT_XM + lxs : -1;

    // interior store slot (tzb*txb <= 91 < NTHREADS: one slot)
    int st_g = -1, st_e = 0, st_l = 0;
    if (tid < tzb * txb) {
        int liz = tid / txb, lix = tid - liz * txb;
        st_g = (z0 + liz) * NXP + (x0 + lix);
        st_e = (liz + HALO) * EXT_XM + (lix + HALO);
        st_l = liz * TX + lix;
    }

    for (int rc = tid; rc < TZ * TX; rc += NTHREADS) lill[rc] = 0.0f;
    __syncthreads();

    // ---- time loop: K-step trapezoid chunks, single-round grid barrier ----
    int t0 = 0, parity = 0;
    unsigned chunk = 0;
    while (t0 < nt) {
        const int ks = (nt - t0 >= KSTEPS) ? KSTEPS : (nt - t0);
        const bool last = (t0 + ks >= nt);
        float* srcb = parity ? buf1 : buf0;
        float* dstb = last ? fields_out : (parity ? buf0 : buf1);

        // load ext tile (coherent agent-scope loads)
#pragma unroll
        for (int k = 0; k < SLOTS; ++k) if (izA[k] >= 0) {
            int rc = rcA[k], g = gA[k];
            lds[0][rc] = aload(&srcb[0 * NCELL + g]);
            lds[1][rc] = aload(&srcb[1 * NCELL + g]);
            lds[2][rc] = aload(&srcb[2 * NCELL + g]);
            lds[3][rc] = aload(&srcb[3 * NCELL + g]);
            lds[4][rc] = aload(&srcb[4 * NCELL + g]);
        }
        __syncthreads();

        for (int p = 1; p <= 2 * ks; ++p) {
            const int t = t0 + ((p + 1) >> 1) - 1;
            const int lo = p, hiZ = ez - p, hiX = extx - p;
            if (p & 1) {
                // velocity phase
#pragma unroll
                for (int k = 0; k < SLOTS; ++k) {
                    int iz = izA[k], ix = ixA[k];
                    if (iz < lo || iz >= hiZ || ix < lo || ix >= hiX) continue;
                    int rc = rcA[k];
                    float bv = cb[k], dv = cd[k];
                    float t1 = lds[2][rc + 1]      - lds[2][rc];
                    float t2 = lds[4][rc]          - lds[4][rc - EXT_XM];
                    float nvx = (lds[0][rc] + bv * (t1 + t2)) * dv;
                    float t3 = lds[3][rc + EXT_XM] - lds[3][rc];
                    float t4 = lds[4][rc]          - lds[4][rc - 1];
                    float nvz = (lds[1][rc] + bv * (t3 + t4)) * dv;
                    lds[0][rc] = nvx;
                    lds[1][rc] = nvz;
                    if (seisA[k] >= 0) seismo[t * NXI + seisA[k]] = nvz;
                }
            } else {
                // stress phase
#pragma unroll
                for (int k = 0; k < SLOTS; ++k) {
                    int iz = izA[k], ix = ixA[k];
                    if (iz < lo || iz >= hiZ || ix < lo || ix >= hiX) continue;
                    int rc = rcA[k];
                    float dv = cd[k];
                    float exx = lds[0][rc] - lds[0][rc - 1];
                    float ezz = lds[1][rc] - lds[1][rc - EXT_XM];
                    float e1 = cca[k] * exx;
                    float e2 = ccl[k] * ezz;
                    float ntxx = (lds[2][rc] + dtx * (e1 + e2)) * dv;
                    float e3 = ccl[k] * exx;
                    float e4 = cca[k] * ezz;
                    float ntzz = (lds[3][rc] + dtx * (e3 + e4)) * dv;
                    float p1 = lds[0][rc + EXT_XM] - lds[0][rc];
                    float p2 = lds[1][rc + 1]      - lds[1][rc];
                    float ntxz = (lds[4][rc] + cdtcm[k] * (p1 + p2)) * dv;
                    if (rc == src_rc) {
                        float sv = s[t] * dt;
                        ntxx += sv;
                        ntzz += sv;
                    }
                    lds[2][rc] = ntxx;
                    lds[3][rc] = ntzz;
                    lds[4][rc] = ntxz;
                    if (lilA[k] >= 0) {
                        float divv = exx + ezz;
                        lill[lilA[k]] += divv * divv;
                    }
                }
            }
            __syncthreads();
        }

        // store interior (coherent agent-scope stores)
        if (st_g >= 0) {
            astore(&dstb[0 * NCELL + st_g], lds[0][st_e]);
            astore(&dstb[1 * NCELL + st_g], lds[1][st_e]);
            astore(&dstb[2 * NCELL + st_g], lds[2][st_e]);
            astore(&dstb[3 * NCELL + st_g], lds[3][st_e]);
            astore(&dstb[4 * NCELL + st_g], lds[4][st_e]);
            if (last) illum_out[st_g] = lill[st_l];
        }

        t0 += ks; parity ^= 1; ++chunk;

        if (!last) {
            // drain own stores to coherence point, then publish; all-to-all poll
            asm volatile("s_waitcnt vmcnt(0)" ::: "memory");
            __syncthreads();
            if (tid == 0)
                __hip_atomic_store(&flags[bid], chunk, __ATOMIC_RELAXED, AGENT);
            if (tid < NBLOCKS) {
                while (__hip_atomic_load(&flags[tid], __ATOMIC_RELAXED, AGENT) < chunk)
                    __builtin_amdgcn_s_sleep(2);
            }
            __syncthreads();
        }
    }
}

extern "C" void kernel_launch(void* const* d_in, const int* in_sizes, int n_in,
                              void* d_out, int out_size, void* d_ws, size_t ws_size,
                              hipStream_t stream) {
    const float* vp   = (const float*)d_in[0];
    const float* vs   = (const float*)d_in[1];
    const float* den  = (const float*)d_in[2];
    const float* ivec = (const float*)d_in[3];
    const float* temp = (const float*)d_in[4];
    const float* s    = (const float*)d_in[5];
    const int*   isz  = (const int*)d_in[7];
    const int*   isx  = (const int*)d_in[8];
    int nt = in_sizes[5];

    float* out    = (float*)d_out;
    float* fields = out;                        // uu1: 5*NCELL
    float* seismo = out + 5 * NCELL;            // nt*NXI
    float* illum  = seismo + (size_t)nt * NXI;  // NCELL

    float* ws    = (float*)d_ws;
    float* coeff = ws;                 // 5*NCELL
    float* buf0  = ws + 5 * NCELL;     // 5*NCELL
    float* buf1  = ws + 10 * NCELL;    // 5*NCELL
    unsigned* flags = (unsigned*)(ws + 15 * NCELL);   // NBLOCKS

    setup_kernel<<<(NCELL + 255) / 256, 256, 0, stream>>>(
        vp, vs, den, ivec, temp, coeff, buf0, flags);

    persist_kernel<<<NBLOCKS, NTHREADS, 0, stream>>>(
        coeff, buf0, buf1, ivec, s, isz, isx,
        fields, illum, seismo, flags, nt);
}

// Round 6
// 3296.842 us; speedup vs baseline: 1.1411x; 1.1411x over previous
//
#include <hip/hip_runtime.h>

#define NPADC 40
#define NZ 26
#define NXI 120            // interior nx (seismo width)
#define NZP 106
#define NXP 200
#define NCELL (NZP * NXP)

#define KSTEPS 5
#define HALO (2 * KSTEPS)          // 10
// z tiles: 6 of 11 + 4 of 10 (all >= HALO); x tiles: 20 of 10
#define NZB 10
#define NXB 20
#define NBLOCKS (NZB * NXB)        // 200
#define TXB 10                     // constant x tile size
#define EXT_XM (TXB + 2 * HALO)    // 30 (constant LDS row stride)
#define EZMAX (11 + 2 * HALO)      // 31
#define LDSN (EZMAX * EXT_XM)      // 930
#define NTHREADS 256
#define SLOTS 4                    // ceil(930/256)
#define FLAGSTRIDE 32              // uints -> 128 B per flag line

#define AGENT __HIP_MEMORY_SCOPE_AGENT

__device__ __forceinline__ float aload(float* p) {
    return __hip_atomic_load(p, __ATOMIC_RELAXED, AGENT);
}
__device__ __forceinline__ void astore(float* p, float v) {
    __hip_atomic_store(p, v, __ATOMIC_RELAXED, AGENT);
}

// ---- damp profile, matching _damp_profile in fp32 ----
__device__ __forceinline__ float dprof(int idx, int n) {
#pragma clang fp contract(off)
    float fi = (float)idx;
    float left = 1.0f, right = 1.0f;
    if (idx < NPADC) {
        float a = 0.015f * ((float)NPADC - fi);
        left = expf(-(a * a));
    }
    if (idx >= n - NPADC) {
        float a = 0.015f * (fi - (float)(n - NPADC - 1));
        right = expf(-(a * a));
    }
    return left * right;
}

// ---- one-time setup: coefficients into ws, init state buf0, zero flags ----
__global__ void setup_kernel(const float* __restrict__ vp,
                             const float* __restrict__ vs,
                             const float* __restrict__ den,
                             const float* __restrict__ ivec,
                             const float* __restrict__ temp,
                             float* __restrict__ coeff,
                             float* __restrict__ buf0,
                             unsigned* __restrict__ flags) {
#pragma clang fp contract(off)
    int i = blockIdx.x * blockDim.x + threadIdx.x;
    if (i < NBLOCKS * FLAGSTRIDE) flags[i] = 0u;
    if (i >= NCELL) return;
    int z = i / NXP;
    int x = i - z * NXP;

    float dtx = ivec[3];

    int zi = z - NPADC; zi = zi < 0 ? 0 : (zi > NZ - 1 ? NZ - 1 : zi);
    int xi = x - NPADC; xi = xi < 0 ? 0 : (xi > NXI - 1 ? NXI - 1 : xi);
    float vpv = vp[zi * NXI + xi];
    float vsv = vs[zi * NXI + xi];
    float d = den[i];

    float cav = (vpv * vpv) * d;     // ca
    float cmv = (vsv * vsv) * d;     // cm
    coeff[0 * NCELL + i] = dtx / d;                        // b
    coeff[1 * NCELL + i] = dprof(z, NZP) * dprof(x, NXP);  // damp
    coeff[2 * NCELL + i] = cav;                            // ca
    coeff[3 * NCELL + i] = cav - 2.0f * cmv;               // cl
    coeff[4 * NCELL + i] = dtx * cmv;                      // dtx*cm

    for (int f = 0; f < 5; ++f)
        buf0[f * NCELL + i] = temp[f * NCELL + i];
}

// lds field order: 0=vx 1=vz 2=txx 3=tzz 4=txz ; coeffs live in registers
__global__ __launch_bounds__(NTHREADS)
void persist_kernel(const float* __restrict__ coeff,
                    float* __restrict__ buf0, float* __restrict__ buf1,
                    const float* __restrict__ ivec, const float* __restrict__ s,
                    const int* __restrict__ iszp, const int* __restrict__ isxp,
                    float* __restrict__ fields_out,
                    float* __restrict__ illum_out,
                    float* __restrict__ seismo,
                    unsigned* __restrict__ flags,
                    int nt) {
#pragma clang fp contract(off)
    __shared__ float lds[5][LDSN];
    __shared__ float lill[11 * TXB];

    const int tid = threadIdx.x;
    const int bid = blockIdx.x;
    const int zb = bid / NXB, xb = bid - zb * NXB;
    const int z0  = (zb < 6) ? 11 * zb : 66 + (zb - 6) * 10;
    const int tzb = (zb < 6) ? 11 : 10;
    const int x0  = xb * TXB;
    const int txb = TXB;
    const int ez  = tzb + 2 * HALO;                      // 31 or 30
    const int ncl = ez * EXT_XM;
    const float dt  = ivec[2];
    const float dtx = ivec[3];
    const int isz = *iszp, isx = *isxp;

    // ---- per-thread slot precompute (coords, wrap, ownership, coeffs) ----
    int rcA[SLOTS], gA[SLOTS], izA[SLOTS], ixA[SLOTS], seisA[SLOTS], lilA[SLOTS];
    float cb[SLOTS], cd[SLOTS], cca[SLOTS], ccl[SLOTS], cdtcm[SLOTS];
#pragma unroll
    for (int k = 0; k < SLOTS; ++k) {
        int rc = tid + k * NTHREADS;
        rcA[k] = rc;
        int iz = rc / EXT_XM, ix = rc - iz * EXT_XM;
        if (rc < ncl) {
            izA[k] = iz; ixA[k] = ix;
            int gz = z0 - HALO + iz; gz += (gz < 0) ? NZP : 0; gz -= (gz >= NZP) ? NZP : 0;
            int gx = x0 - HALO + ix; gx += (gx < 0) ? NXP : 0; gx -= (gx >= NXP) ? NXP : 0;
            int g = gz * NXP + gx;
            gA[k] = g;
            cb[k]    = coeff[0 * NCELL + g];
            cd[k]    = coeff[1 * NCELL + g];
            cca[k]   = coeff[2 * NCELL + g];
            ccl[k]   = coeff[3 * NCELL + g];
            cdtcm[k] = coeff[4 * NCELL + g];
            int liz = iz - HALO, lix = ix - HALO;
            bool inter = (liz >= 0 && liz < tzb && lix >= 0 && lix < txb);
            int gzi = z0 + liz, gxi = x0 + lix;
            seisA[k] = (inter && gzi == NPADC + 1 && gxi >= NPADC && gxi < NPADC + NXI)
                           ? (gxi - NPADC) : -1;
            lilA[k] = inter ? (liz * txb + lix) : -1;
        } else {
            izA[k] = -1000; ixA[k] = -1000; gA[k] = 0; seisA[k] = -1; lilA[k] = -1;
            cb[k] = cd[k] = cca[k] = ccl[k] = cdtcm[k] = 0.0f;
        }
    }
    // source cell local index (injective: ez<=31<NZP, EXT_XM=30<NXP)
    int lzs = isz - (z0 - HALO); lzs = ((lzs % NZP) + NZP) % NZP;
    int lxs = isx - (x0 - HALO); lxs = ((lxs % NXP) + NXP) % NXP;
    const int src_rc = (lzs < ez && lxs < EXT_XM) ? lzs * EXT_XM + lxs : -1;

    // interior store slot (tzb*txb <= 110 < NTHREADS: one slot; st_l == tid)
    int st_g = -1, st_e = 0;
    if (tid < tzb * txb) {
        int liz = tid / txb, lix = tid - liz * txb;
        st_g = (z0 + liz) * NXP + (x0 + lix);
        st_e = (liz + HALO) * EXT_XM + (lix + HALO);
    }

    // 8-neighbor flag offsets (ring-1, periodic)
    int nbflag = -1;
    if (tid < 8) {
        int idx = (tid < 4) ? tid : tid + 1;      // skip (0,0)
        int dz = idx / 3 - 1, dx = idx % 3 - 1;
        int nzb = zb + dz; nzb += (nzb < 0) ? NZB : 0; nzb -= (nzb >= NZB) ? NZB : 0;
        int nxb = xb + dx; nxb += (nxb < 0) ? NXB : 0; nxb -= (nxb >= NXB) ? NXB : 0;
        nbflag = (nzb * NXB + nxb) * FLAGSTRIDE;
    }

    for (int rc = tid; rc < 11 * TXB; rc += NTHREADS) lill[rc] = 0.0f;
    __syncthreads();

    // ---- time loop: K-step trapezoid chunks, neighbor-only pipelined sync ----
    int t0 = 0, parity = 0;
    unsigned chunk = 0;
    while (t0 < nt) {
        const int ks = (nt - t0 >= KSTEPS) ? KSTEPS : (nt - t0);
        const bool last = (t0 + ks >= nt);
        float* srcb = parity ? buf1 : buf0;
        float* dstb = last ? fields_out : (parity ? buf0 : buf1);

        // load ext tile (coherent agent-scope loads)
#pragma unroll
        for (int k = 0; k < SLOTS; ++k) if (izA[k] >= 0) {
            int rc = rcA[k], g = gA[k];
            lds[0][rc] = aload(&srcb[0 * NCELL + g]);
            lds[1][rc] = aload(&srcb[1 * NCELL + g]);
            lds[2][rc] = aload(&srcb[2 * NCELL + g]);
            lds[3][rc] = aload(&srcb[3 * NCELL + g]);
            lds[4][rc] = aload(&srcb[4 * NCELL + g]);
        }
        __syncthreads();

        for (int p = 1; p <= 2 * ks; ++p) {
            const int t = t0 + ((p + 1) >> 1) - 1;
            const int lo = p, hiZ = ez - p, hiX = EXT_XM - p;
            if (p & 1) {
                // velocity phase
#pragma unroll
                for (int k = 0; k < SLOTS; ++k) {
                    int iz = izA[k], ix = ixA[k];
                    if (iz < lo || iz >= hiZ || ix < lo || ix >= hiX) continue;
                    int rc = rcA[k];
                    float bv = cb[k], dv = cd[k];
                    float t1 = lds[2][rc + 1]      - lds[2][rc];
                    float t2 = lds[4][rc]          - lds[4][rc - EXT_XM];
                    float nvx = (lds[0][rc] + bv * (t1 + t2)) * dv;
                    float t3 = lds[3][rc + EXT_XM] - lds[3][rc];
                    float t4 = lds[4][rc]          - lds[4][rc - 1];
                    float nvz = (lds[1][rc] + bv * (t3 + t4)) * dv;
                    lds[0][rc] = nvx;
                    lds[1][rc] = nvz;
                    if (seisA[k] >= 0) seismo[t * NXI + seisA[k]] = nvz;
                }
            } else {
                // stress phase
#pragma unroll
                for (int k = 0; k < SLOTS; ++k) {
                    int iz = izA[k], ix = ixA[k];
                    if (iz < lo || iz >= hiZ || ix < lo || ix >= hiX) continue;
                    int rc = rcA[k];
                    float dv = cd[k];
                    float exx = lds[0][rc] - lds[0][rc - 1];
                    float ezz = lds[1][rc] - lds[1][rc - EXT_XM];
                    float e1 = cca[k] * exx;
                    float e2 = ccl[k] * ezz;
                    float ntxx = (lds[2][rc] + dtx * (e1 + e2)) * dv;
                    float e3 = ccl[k] * exx;
                    float e4 = cca[k] * ezz;
                    float ntzz = (lds[3][rc] + dtx * (e3 + e4)) * dv;
                    float p1 = lds[0][rc + EXT_XM] - lds[0][rc];
                    float p2 = lds[1][rc + 1]      - lds[1][rc];
                    float ntxz = (lds[4][rc] + cdtcm[k] * (p1 + p2)) * dv;
                    if (rc == src_rc) {
                        float sv = s[t] * dt;
                        ntxx += sv;
                        ntzz += sv;
                    }
                    lds[2][rc] = ntxx;
                    lds[3][rc] = ntzz;
                    lds[4][rc] = ntxz;
                    if (lilA[k] >= 0) {
                        float divv = exx + ezz;
                        lill[lilA[k]] += divv * divv;
                    }
                }
            }
            __syncthreads();
        }

        // store interior (coherent agent-scope stores)
        if (st_g >= 0) {
            astore(&dstb[0 * NCELL + st_g], lds[0][st_e]);
            astore(&dstb[1 * NCELL + st_g], lds[1][st_e]);
            astore(&dstb[2 * NCELL + st_g], lds[2][st_e]);
            astore(&dstb[3 * NCELL + st_g], lds[3][st_e]);
            astore(&dstb[4 * NCELL + st_g], lds[4][st_e]);
            if (last) illum_out[st_g] = lill[tid];
        }

        t0 += ks; parity ^= 1; ++chunk;

        if (!last) {
            // publish own completion, then wait only for 8 ring neighbors
            asm volatile("s_waitcnt vmcnt(0)" ::: "memory");
            __syncthreads();   // all waves' stores drained before publish
            if (tid == 0)
                __hip_atomic_store(&flags[bid * FLAGSTRIDE], chunk,
                                   __ATOMIC_RELAXED, AGENT);
            if (tid < 8) {
                while (__hip_atomic_load(&flags[nbflag], __ATOMIC_RELAXED, AGENT)
                       < chunk)
                    __builtin_amdgcn_s_sleep(1);
            }
            asm volatile("" ::: "memory");
            __syncthreads();
        }
    }
}

extern "C" void kernel_launch(void* const* d_in, const int* in_sizes, int n_in,
                              void* d_out, int out_size, void* d_ws, size_t ws_size,
                              hipStream_t stream) {
    const float* vp   = (const float*)d_in[0];
    const float* vs   = (const float*)d_in[1];
    const float* den  = (const float*)d_in[2];
    const float* ivec = (const float*)d_in[3];
    const float* temp = (const float*)d_in[4];
    const float* s    = (const float*)d_in[5];
    const int*   isz  = (const int*)d_in[7];
    const int*   isx  = (const int*)d_in[8];
    int nt = in_sizes[5];

    float* out    = (float*)d_out;
    float* fields = out;                        // uu1: 5*NCELL
    float* seismo = out + 5 * NCELL;            // nt*NXI
    float* illum  = seismo + (size_t)nt * NXI;  // NCELL

    float* ws    = (float*)d_ws;
    float* coeff = ws;                 // 5*NCELL
    float* buf0  = ws + 5 * NCELL;     // 5*NCELL
    float* buf1  = ws + 10 * NCELL;    // 5*NCELL
    unsigned* flags = (unsigned*)(ws + 15 * NCELL);   // NBLOCKS*FLAGSTRIDE

    setup_kernel<<<(NCELL + 255) / 256, 256, 0, stream>>>(
        vp, vs, den, ivec, temp, coeff, buf0, flags);

    persist_kernel<<<NBLOCKS, NTHREADS, 0, stream>>>(
        coeff, buf0, buf1, ivec, s, isz, isx,
        fields, illum, seismo, flags, nt);
}

// Round 7
// 1689.555 us; speedup vs baseline: 2.2266x; 1.9513x over previous
//
#include <hip/hip_runtime.h>

#define NPADC 40
#define NZ 26
#define NXI 120            // interior nx (seismo width)
#define NZP 106
#define NXP 200
#define NCELL (NZP * NXP)

#define KSTEPS 5
#define HALO (2 * KSTEPS)          // 10
// z tiles: 6 of 11 + 4 of 10 (all >= HALO); x tiles: 20 of 10
#define NZB 10
#define NXB 20
#define NBLOCKS (NZB * NXB)        // 200
#define TXB 10                     // constant x tile size
#define EXT_XM (TXB + 2 * HALO)    // 30 (constant LDS row stride)
#define EZMAX (11 + 2 * HALO)      // 31
#define LDSN (EZMAX * EXT_XM)      // 930
#define NTHREADS 1024              // one thread per ext-tile cell
#define FLAGSTRIDE 32              // uints -> 128 B per flag line

#define AGENT __HIP_MEMORY_SCOPE_AGENT

__device__ __forceinline__ float aload(float* p) {
    return __hip_atomic_load(p, __ATOMIC_RELAXED, AGENT);
}
__device__ __forceinline__ void astore(float* p, float v) {
    __hip_atomic_store(p, v, __ATOMIC_RELAXED, AGENT);
}

// ---- damp profile, matching _damp_profile in fp32 ----
__device__ __forceinline__ float dprof(int idx, int n) {
#pragma clang fp contract(off)
    float fi = (float)idx;
    float left = 1.0f, right = 1.0f;
    if (idx < NPADC) {
        float a = 0.015f * ((float)NPADC - fi);
        left = expf(-(a * a));
    }
    if (idx >= n - NPADC) {
        float a = 0.015f * (fi - (float)(n - NPADC - 1));
        right = expf(-(a * a));
    }
    return left * right;
}

// ---- one-time setup: coefficients into ws, init state buf0, zero flags ----
__global__ void setup_kernel(const float* __restrict__ vp,
                             const float* __restrict__ vs,
                             const float* __restrict__ den,
                             const float* __restrict__ ivec,
                             const float* __restrict__ temp,
                             float* __restrict__ coeff,
                             float* __restrict__ buf0,
                             unsigned* __restrict__ flags) {
#pragma clang fp contract(off)
    int i = blockIdx.x * blockDim.x + threadIdx.x;
    if (i < NBLOCKS * FLAGSTRIDE) flags[i] = 0u;
    if (i >= NCELL) return;
    int z = i / NXP;
    int x = i - z * NXP;

    float dtx = ivec[3];

    int zi = z - NPADC; zi = zi < 0 ? 0 : (zi > NZ - 1 ? NZ - 1 : zi);
    int xi = x - NPADC; xi = xi < 0 ? 0 : (xi > NXI - 1 ? NXI - 1 : xi);
    float vpv = vp[zi * NXI + xi];
    float vsv = vs[zi * NXI + xi];
    float d = den[i];

    float cav = (vpv * vpv) * d;     // ca
    float cmv = (vsv * vsv) * d;     // cm
    coeff[0 * NCELL + i] = dtx / d;                        // b
    coeff[1 * NCELL + i] = dprof(z, NZP) * dprof(x, NXP);  // damp
    coeff[2 * NCELL + i] = cav;                            // ca
    coeff[3 * NCELL + i] = cav - 2.0f * cmv;               // cl
    coeff[4 * NCELL + i] = dtx * cmv;                      // dtx*cm

    for (int f = 0; f < 5; ++f)
        buf0[f * NCELL + i] = temp[f * NCELL + i];
}

// lds field order: 0=vx 1=vz 2=txx 3=tzz 4=txz ; coeffs + illum in registers
__global__ __launch_bounds__(NTHREADS)
void persist_kernel(const float* __restrict__ coeff,
                    float* __restrict__ buf0, float* __restrict__ buf1,
                    const float* __restrict__ ivec, const float* __restrict__ s,
                    const int* __restrict__ iszp, const int* __restrict__ isxp,
                    float* __restrict__ fields_out,
                    float* __restrict__ illum_out,
                    float* __restrict__ seismo,
                    unsigned* __restrict__ flags,
                    int nt) {
#pragma clang fp contract(off)
    __shared__ float lds[5][LDSN];

    const int tid = threadIdx.x;
    const int bid = blockIdx.x;
    const int zb = bid / NXB, xb = bid - zb * NXB;
    const int z0  = (zb < 6) ? 11 * zb : 66 + (zb - 6) * 10;
    const int tzb = (zb < 6) ? 11 : 10;
    const int x0  = xb * TXB;
    const int ez  = tzb + 2 * HALO;                      // 31 or 30
    const int ncl = ez * EXT_XM;
    const float dt  = ivec[2];
    const float dtx = ivec[3];
    const int isz = *iszp, isx = *isxp;

    // ---- per-thread cell precompute (one cell per thread) ----
    const int rc = tid;
    const bool valid = rc < ncl;
    int izv = -1000, ixv = -1000, g = 0, seis = -1;
    bool inter = false;
    float cb = 0.f, cd = 0.f, cca = 0.f, ccl = 0.f, cdtcm = 0.f;
    if (valid) {
        int iz = rc / EXT_XM, ix = rc - iz * EXT_XM;
        izv = iz; ixv = ix;
        int gz = z0 - HALO + iz; gz += (gz < 0) ? NZP : 0; gz -= (gz >= NZP) ? NZP : 0;
        int gx = x0 - HALO + ix; gx += (gx < 0) ? NXP : 0; gx -= (gx >= NXP) ? NXP : 0;
        g = gz * NXP + gx;
        cb    = coeff[0 * NCELL + g];
        cd    = coeff[1 * NCELL + g];
        cca   = coeff[2 * NCELL + g];
        ccl   = coeff[3 * NCELL + g];
        cdtcm = coeff[4 * NCELL + g];
        int liz = iz - HALO, lix = ix - HALO;
        inter = (liz >= 0 && liz < tzb && lix >= 0 && lix < TXB);
        int gzi = z0 + liz, gxi = x0 + lix;
        seis = (inter && gzi == NPADC + 1 && gxi >= NPADC && gxi < NPADC + NXI)
                   ? (gxi - NPADC) : -1;
    }
    // source cell local index (injective: ez<=31<NZP, EXT_XM=30<NXP)
    int lzs = isz - (z0 - HALO); lzs = ((lzs % NZP) + NZP) % NZP;
    int lxs = isx - (x0 - HALO); lxs = ((lxs % NXP) + NXP) % NXP;
    const int src_rc = (lzs < ez && lxs < EXT_XM) ? lzs * EXT_XM + lxs : -1;

    // 8-neighbor flag offsets (ring-1, periodic)
    int nbflag = -1;
    if (tid < 8) {
        int idx = (tid < 4) ? tid : tid + 1;      // skip (0,0)
        int dz = idx / 3 - 1, dx = idx % 3 - 1;
        int nzb = zb + dz; nzb += (nzb < 0) ? NZB : 0; nzb -= (nzb >= NZB) ? NZB : 0;
        int nxb = xb + dx; nxb += (nxb < 0) ? NXB : 0; nxb -= (nxb >= NXB) ? NXB : 0;
        nbflag = (nzb * NXB + nxb) * FLAGSTRIDE;
    }

    float ilacc = 0.0f;   // per-thread illum accumulator (interior cells only)

    // ---- time loop: K-step trapezoid chunks, neighbor-only pipelined sync ----
    int t0 = 0, parity = 0;
    unsigned chunk = 0;
    while (t0 < nt) {
        const int ks = (nt - t0 >= KSTEPS) ? KSTEPS : (nt - t0);
        const bool last = (t0 + ks >= nt);
        float* srcb = parity ? buf1 : buf0;
        float* dstb = last ? fields_out : (parity ? buf0 : buf1);

        // load ext tile (coherent agent-scope loads)
        if (valid) {
            lds[0][rc] = aload(&srcb[0 * NCELL + g]);
            lds[1][rc] = aload(&srcb[1 * NCELL + g]);
            lds[2][rc] = aload(&srcb[2 * NCELL + g]);
            lds[3][rc] = aload(&srcb[3 * NCELL + g]);
            lds[4][rc] = aload(&srcb[4 * NCELL + g]);
        }
        __syncthreads();

        for (int p = 1; p <= 2 * ks; ++p) {
            const int t = t0 + ((p + 1) >> 1) - 1;
            const bool act = (izv >= p) && (izv < ez - p) &&
                             (ixv >= p) && (ixv < EXT_XM - p);
            if (p & 1) {
                // velocity phase
                if (act) {
                    float t1 = lds[2][rc + 1]      - lds[2][rc];
                    float t2 = lds[4][rc]          - lds[4][rc - EXT_XM];
                    float nvx = (lds[0][rc] + cb * (t1 + t2)) * cd;
                    float t3 = lds[3][rc + EXT_XM] - lds[3][rc];
                    float t4 = lds[4][rc]          - lds[4][rc - 1];
                    float nvz = (lds[1][rc] + cb * (t3 + t4)) * cd;
                    lds[0][rc] = nvx;
                    lds[1][rc] = nvz;
                    if (seis >= 0) seismo[t * NXI + seis] = nvz;
                }
            } else {
                // stress phase
                if (act) {
                    float exx = lds[0][rc] - lds[0][rc - 1];
                    float ezz = lds[1][rc] - lds[1][rc - EXT_XM];
                    float e1 = cca * exx;
                    float e2 = ccl * ezz;
                    float ntxx = (lds[2][rc] + dtx * (e1 + e2)) * cd;
                    float e3 = ccl * exx;
                    float e4 = cca * ezz;
                    float ntzz = (lds[3][rc] + dtx * (e3 + e4)) * cd;
                    float p1 = lds[0][rc + EXT_XM] - lds[0][rc];
                    float p2 = lds[1][rc + 1]      - lds[1][rc];
                    float ntxz = (lds[4][rc] + cdtcm * (p1 + p2)) * cd;
                    if (rc == src_rc) {
                        float sv = s[t] * dt;
                        ntxx += sv;
                        ntzz += sv;
                    }
                    lds[2][rc] = ntxx;
                    lds[3][rc] = ntzz;
                    lds[4][rc] = ntxz;
                    if (inter) {
                        float divv = exx + ezz;
                        ilacc += divv * divv;
                    }
                }
            }
            __syncthreads();
        }

        // store interior (coherent agent-scope stores); each interior thread
        // owns exactly its cell
        if (inter) {
            astore(&dstb[0 * NCELL + g], lds[0][rc]);
            astore(&dstb[1 * NCELL + g], lds[1][rc]);
            astore(&dstb[2 * NCELL + g], lds[2][rc]);
            astore(&dstb[3 * NCELL + g], lds[3][rc]);
            astore(&dstb[4 * NCELL + g], lds[4][rc]);
            if (last) illum_out[g] = ilacc;
        }

        t0 += ks; parity ^= 1; ++chunk;

        if (!last) {
            // publish own completion, then wait only for 8 ring neighbors
            asm volatile("s_waitcnt vmcnt(0)" ::: "memory");
            __syncthreads();   // all waves' stores drained before publish
            if (tid == 0)
                __hip_atomic_store(&flags[bid * FLAGSTRIDE], chunk,
                                   __ATOMIC_RELAXED, AGENT);
            if (tid < 8) {
                while (__hip_atomic_load(&flags[nbflag], __ATOMIC_RELAXED, AGENT)
                       < chunk)
                    __builtin_amdgcn_s_sleep(1);
            }
            asm volatile("" ::: "memory");
            __syncthreads();
        }
    }
}

extern "C" void kernel_launch(void* const* d_in, const int* in_sizes, int n_in,
                              void* d_out, int out_size, void* d_ws, size_t ws_size,
                              hipStream_t stream) {
    const float* vp   = (const float*)d_in[0];
    const float* vs   = (const float*)d_in[1];
    const float* den  = (const float*)d_in[2];
    const float* ivec = (const float*)d_in[3];
    const float* temp = (const float*)d_in[4];
    const float* s    = (const float*)d_in[5];
    const int*   isz  = (const int*)d_in[7];
    const int*   isx  = (const int*)d_in[8];
    int nt = in_sizes[5];

    float* out    = (float*)d_out;
    float* fields = out;                        // uu1: 5*NCELL
    float* seismo = out + 5 * NCELL;            // nt*NXI
    float* illum  = seismo + (size_t)nt * NXI;  // NCELL

    float* ws    = (float*)d_ws;
    float* coeff = ws;                 // 5*NCELL
    float* buf0  = ws + 5 * NCELL;     // 5*NCELL
    float* buf1  = ws + 10 * NCELL;    // 5*NCELL
    unsigned* flags = (unsigned*)(ws + 15 * NCELL);   // NBLOCKS*FLAGSTRIDE

    setup_kernel<<<(NCELL + 255) / 256, 256, 0, stream>>>(
        vp, vs, den, ivec, temp, coeff, buf0, flags);

    persist_kernel<<<NBLOCKS, NTHREADS, 0, stream>>>(
        coeff, buf0, buf1, ivec, s, isz, isx,
        fields, illum, seismo, flags, nt);
}